// Round 5
// baseline (398.704 us; speedup 1.0000x reference)
//
#include <hip/hip_runtime.h>
#include <hip/hip_bf16.h>
#include <cstdint>

// AttentionPooling, fused single-HBM-pass over x.
// Per 64-row chunk: stage x->LDS(f16) -> MFMA scores (A from LDS, W1 B-frags
// streamed from L2 each chunk) -> online softmax (wave 0) -> column-range
// accumulation from LDS (half8 vector reads, fma_mix).
// Register budget kept ~80 VGPRs so __launch_bounds__(256,4) has no spills.

#define H_DIM 256
#define HID   128
#define CHUNK 64
#define XT_STRIDE 264   // f16 per row: 256 + 8 pad (row stride 528B, 16B-aligned)

typedef _Float16 half8 __attribute__((ext_vector_type(8)));
typedef _Float16 half4 __attribute__((ext_vector_type(4)));
typedef float floatx4 __attribute__((ext_vector_type(4)));

__device__ __forceinline__ float fast_tanh(float y) {
    float e2 = __expf(2.0f * y);
    return 1.0f - 2.0f / (e2 + 1.0f);
}

// ---------------------------------------------------------------- prep_w1
// idx = ((nt*8 + ks)*64 + lane)*8 + j  <->  W1[k][n], k = ks*32+(lane>>4)*8+j,
// n = nt*16 + (lane&15)
__global__ void prep_w1(const float* __restrict__ W1, _Float16* __restrict__ w1h) {
    int idx = blockIdx.x * blockDim.x + threadIdx.x;
    if (idx >= 8 * 8 * 64 * 8) return;
    int j  = idx & 7;
    int l  = (idx >> 3) & 63;
    int ks = (idx >> 9) & 7;
    int nt = idx >> 12;
    int k = ks * 32 + ((l >> 4) << 3) + j;
    int n = nt * 16 + (l & 15);
    w1h[idx] = (_Float16)W1[k * HID + n];
}

// ---------------------------------------------------------------- fused
__global__ __launch_bounds__(256, 4) void fused_kernel(
    const float* __restrict__ x, const _Float16* __restrict__ w1h,
    const float* __restrict__ b1, const float* __restrict__ W2,
    const float* __restrict__ b2, const int* __restrict__ batch,
    float* __restrict__ out, int N)
{
    __shared__ __align__(16) _Float16 xt[CHUNK * XT_STRIDE]; // 33.8KB chunk tile
    __shared__ float pbuf[4][CHUNK];                         // per-wave score partials
    __shared__ float wbuf[CHUNK];                            // chunk exp-weights
    __shared__ float fz[2];                                  // rescale f, final Z

    int tid = threadIdx.x, b = blockIdx.x;
    int wave = tid >> 6, lane = tid & 63, g = lane >> 4, c = lane & 15;
    int colg = tid & 31, rowg = tid >> 5;   // accumulation mapping

    // segment bounds (batch sorted)
    int lo = 0, hi = N;
    while (lo < hi) { int mid = (lo + hi) >> 1; if (batch[mid] < b) lo = mid + 1; else hi = mid; }
    int start = lo; hi = N;
    while (lo < hi) { int mid = (lo + hi) >> 1; if (batch[mid] <= b) lo = mid + 1; else hi = mid; }
    int end = lo;
    int seglen = end - start;
    if (seglen <= 0) { out[(size_t)b * H_DIM + tid] = 0.0f; return; }

    float b1r[2], w2r[2];
#pragma unroll
    for (int nt2 = 0; nt2 < 2; ++nt2) {
        b1r[nt2] = b1[(2 * wave + nt2) * 16 + c];
        w2r[nt2] = W2[(2 * wave + nt2) * 16 + c];
    }
    float b2v = b2[0];

    float m_run = -3.0e38f;   // wave0-uniform running max
    float Zrun  = 0.0f;       // wave0-uniform running Z
    float a[8];               // per-thread accumulators for cols colg*8..colg*8+7
#pragma unroll
    for (int k2 = 0; k2 < 8; ++k2) a[k2] = 0.0f;

    for (int co = 0; co < seglen; co += CHUNK) {
        int cnt = min(CHUNK, seglen - co);

        __syncthreads();   // S1: prior-chunk xt reads complete

        // ---- stage: 64 rows -> f16 LDS tile; 16 float4/thread in 4 batches
#pragma unroll
        for (int bb = 0; bb < 4; ++bb) {
            float4 rv[4];
#pragma unroll
            for (int i = 0; i < 4; ++i) {
                int fi = tid + (bb * 4 + i) * 256;       // float4 slot 0..4095
                int row = fi >> 6, col4 = fi & 63;
                int rr = row < cnt ? row : cnt - 1;      // clamp tail (masked later)
                rv[i] = *(const float4*)(x + (size_t)(start + co + rr) * H_DIM + col4 * 4);
            }
#pragma unroll
            for (int i = 0; i < 4; ++i) {
                int fi = tid + (bb * 4 + i) * 256;
                int row = fi >> 6, col4 = fi & 63;
                half4 hv;
                hv[0] = (_Float16)rv[i].x; hv[1] = (_Float16)rv[i].y;
                hv[2] = (_Float16)rv[i].z; hv[3] = (_Float16)rv[i].w;
                *(half4*)&xt[row * XT_STRIDE + col4 * 4] = hv;
            }
        }

        __syncthreads();   // S2: xt ready

        // ---- scores: 4 m-tiles x 2 n-tiles per wave; B-frags from L2
        floatx4 acc[4][2];
#pragma unroll
        for (int mt = 0; mt < 4; ++mt)
#pragma unroll
            for (int nt2 = 0; nt2 < 2; ++nt2)
#pragma unroll
                for (int q = 0; q < 4; ++q) acc[mt][nt2][q] = 0.0f;

        const half8* bbase = (const half8*)&w1h[((2 * wave * 8) * 64 + lane) * 8];
#pragma unroll
        for (int ks = 0; ks < 8; ++ks) {
            half8 bf0 = bbase[ks * 64];            // nt = 2*wave
            half8 bf1 = bbase[(8 + ks) * 64];      // nt = 2*wave+1
#pragma unroll
            for (int mt = 0; mt < 4; ++mt) {
                half8 af = *(const half8*)&xt[(mt * 16 + c) * XT_STRIDE + ks * 32 + g * 8];
                acc[mt][0] = __builtin_amdgcn_mfma_f32_16x16x32_f16(af, bf0, acc[mt][0], 0, 0, 0);
                acc[mt][1] = __builtin_amdgcn_mfma_f32_16x16x32_f16(af, bf1, acc[mt][1], 0, 0, 0);
            }
        }

        // ---- epilogue: partial score over this wave's 32 hidden units
#pragma unroll
        for (int mt = 0; mt < 4; ++mt) {
#pragma unroll
            for (int r = 0; r < 4; ++r) {
                float p = fast_tanh(acc[mt][0][r] + b1r[0]) * w2r[0]
                        + fast_tanh(acc[mt][1][r] + b1r[1]) * w2r[1];
                p += __shfl_xor(p, 8);
                p += __shfl_xor(p, 4);
                p += __shfl_xor(p, 2);
                p += __shfl_xor(p, 1);
                if (c == 0) pbuf[wave][mt * 16 + g * 4 + r] = p;
            }
        }

        __syncthreads();   // S3: pbuf ready

        // ---- online softmax update (wave 0; lane = chunk row)
        if (wave == 0) {
            float sv = (lane < cnt)
                ? (pbuf[0][lane] + pbuf[1][lane] + pbuf[2][lane] + pbuf[3][lane] + b2v)
                : -3.0e38f;
            float cm = sv;
#pragma unroll
            for (int off = 32; off; off >>= 1) cm = fmaxf(cm, __shfl_xor(cm, off));
            float m_new = fmaxf(m_run, cm);
            float f = __expf(m_run - m_new);      // 0 on first chunk
            float w = __expf(sv - m_new);         // 0 for masked rows
            wbuf[lane] = w;
            float sw = w;
#pragma unroll
            for (int off = 32; off; off >>= 1) sw += __shfl_xor(sw, off);
            Zrun = Zrun * f + sw;
            m_run = m_new;
            if (lane == 0) fz[0] = f;
        }

        __syncthreads();   // S4: wbuf / fz[0] ready

        // ---- accumulation: thread owns cols [colg*8, colg*8+8), rows ≡ rowg mod 8
        float f = fz[0];
#pragma unroll
        for (int k2 = 0; k2 < 8; ++k2) a[k2] *= f;
#pragma unroll
        for (int i = 0; i < 8; ++i) {
            int j = rowg + 8 * i;
            float w = wbuf[j];
            half8 hx = *(const half8*)&xt[j * XT_STRIDE + colg * 8];
#pragma unroll
            for (int k2 = 0; k2 < 8; ++k2)
                a[k2] = fmaf((float)hx[k2], w, a[k2]);
        }
    }

    if (tid == 0) fz[1] = Zrun;

    // ---- final: sum the 8 row-group partials per column (scratch in xt)
    __syncthreads();                      // last accum reads of xt done
    float* scr = (float*)xt;              // [8][256] f32
    *(float4*)&scr[rowg * 256 + colg * 8]     = make_float4(a[0], a[1], a[2], a[3]);
    *(float4*)&scr[rowg * 256 + colg * 8 + 4] = make_float4(a[4], a[5], a[6], a[7]);
    __syncthreads();
    float r = 0.0f;
#pragma unroll
    for (int i = 0; i < 8; ++i) r += scr[i * 256 + tid];
    out[(size_t)b * H_DIM + tid] = r / fz[1];
}

// ---------------------------------------------------------------- launch
extern "C" void kernel_launch(void* const* d_in, const int* in_sizes, int n_in,
                              void* d_out, int out_size, void* d_ws, size_t ws_size,
                              hipStream_t stream) {
    const float* x    = (const float*)d_in[0];
    const float* W1   = (const float*)d_in[1];
    const float* b1   = (const float*)d_in[2];
    const float* W2   = (const float*)d_in[3];
    const float* b2   = (const float*)d_in[4];
    const int*   batch = (const int*)d_in[5];
    int N = in_sizes[5];
    int B = out_size / H_DIM;

    _Float16* w1h = (_Float16*)d_ws;   // 64KB frag-ordered W1

    prep_w1<<<32768 / 256, 256, 0, stream>>>(W1, w1h);
    fused_kernel<<<B, 256, 0, stream>>>(x, w1h, b1, W2, b2, batch, (float*)d_out, N);
}